// Round 1
// baseline (1075.672 us; speedup 1.0000x reference)
//
#include <hip/hip_runtime.h>

// ActionDetokenizer: out[b,j,k] = sum_d x[b, j+1, d] * W[j,d,k] + bias[j,k]
// x: (B,13,256) f32, W: (12,256,2) f32, bias: (12,2) f32, out: (B,12,2) f32.
//
// R4: j-uniform waves + quarter-wave-contiguous full-row consumption.
//  - wave w: j = w%12 (wave-uniform) -> this lane's W fragment (8 float4)
//    preloaded ONCE per wave; bias scalar-loaded once.
//  - 16-lane group g=lane/16 owns row b = t*4+g; lane l=lane&15 owns the
//    16B slice at byte offset l*16 + i*256 (i=0..3). Every VMEM instruction
//    is 4 x 256B contiguous quarter-wave segments; the 4 instructions of an
//    iteration consume all touched 128B lines completely (no L1/L2
//    re-reference, no half-line waste -> fixes R3's 64B-scatter thrash).
//  - per iteration (4 rows = 4KB): 4 loads, 32 FMA, 8 shfl (16-lane reduce
//    of 2 accs = 2 shfl/row), 1 masked float2 store. Double-buffered.
// Memory-bound target: ~805 MB of x -> ~130-200 us at achievable BW.

__global__ __launch_bounds__(256) void detok_kernel(
    const float* __restrict__ x, const float* __restrict__ W,
    const float* __restrict__ bias, float* __restrict__ out,
    int B, int nwpj)
{
    const int lane = (int)(threadIdx.x & 63u);
    const int g = lane >> 4;     // 0..3: row within wave-iteration
    const int l = lane & 15;     // 0..15: 16B-slice owner within row

    const int wid = (int)blockIdx.x * ((int)blockDim.x >> 6) + ((int)threadIdx.x >> 6);
    const int j = wid % 12;      // wave-uniform joint
    const int c = wid / 12;      // chunk index within this j

    const int T = B >> 2;        // number of 4-row groups along b
    if (c >= T) return;

    // W fragments: for i=0..3, d = l*4 + i*64; W flat offset j*512 + d*2.
    // Layout per float4 pair: [d k0, d k1, d+1 k0, d+1 k1][d+2 k0, ...]
    const float* wbase = W + (size_t)j * 512 + l * 8;
    const float4 wa0 = *(const float4*)(wbase + 0);
    const float4 wa1 = *(const float4*)(wbase + 4);
    const float4 wb0 = *(const float4*)(wbase + 128);
    const float4 wb1 = *(const float4*)(wbase + 132);
    const float4 wc0 = *(const float4*)(wbase + 256);
    const float4 wc1 = *(const float4*)(wbase + 260);
    const float4 wd0 = *(const float4*)(wbase + 384);
    const float4 wd1 = *(const float4*)(wbase + 388);

    const float bj0 = bias[j * 2 + 0];
    const float bj1 = bias[j * 2 + 1];

    int t = c;
    const size_t xstep = (size_t)nwpj * 4 * (13 * 256);  // floats per stride
    const size_t ostep = (size_t)nwpj * 4 * 24;

    const float* xp = x + ((size_t)(t * 4 + g) * 13 + (j + 1)) * 256 + l * 4;
    float* op = out + ((size_t)(t * 4 + g) * 12 + j) * 2;

    float4 va = *(const float4*)(xp + 0);
    float4 vb = *(const float4*)(xp + 64);
    float4 vc = *(const float4*)(xp + 128);
    float4 vd = *(const float4*)(xp + 192);

    for (;;) {
        const int tn = t + nwpj;
        const bool more = (tn < T);     // wave-uniform
        float4 ua, ub, uc, ud;
        if (more) {
            const float* xn = xp + xstep;
            ua = *(const float4*)(xn + 0);
            ub = *(const float4*)(xn + 64);
            uc = *(const float4*)(xn + 128);
            ud = *(const float4*)(xn + 192);
        }

        float a0 = va.x * wa0.x + va.y * wa0.z + va.z * wa1.x + va.w * wa1.z;
        float a1 = va.x * wa0.y + va.y * wa0.w + va.z * wa1.y + va.w * wa1.w;
        a0 += vb.x * wb0.x + vb.y * wb0.z + vb.z * wb1.x + vb.w * wb1.z;
        a1 += vb.x * wb0.y + vb.y * wb0.w + vb.z * wb1.y + vb.w * wb1.w;
        a0 += vc.x * wc0.x + vc.y * wc0.z + vc.z * wc1.x + vc.w * wc1.z;
        a1 += vc.x * wc0.y + vc.y * wc0.w + vc.z * wc1.y + vc.w * wc1.w;
        a0 += vd.x * wd0.x + vd.y * wd0.z + vd.z * wd1.x + vd.w * wd1.z;
        a1 += vd.x * wd0.y + vd.y * wd0.w + vd.z * wd1.y + vd.w * wd1.w;

        // 16-lane xor-tree reduce (masks < 16 stay inside the group)
        a0 += __shfl_xor(a0, 1, 64);
        a1 += __shfl_xor(a1, 1, 64);
        a0 += __shfl_xor(a0, 2, 64);
        a1 += __shfl_xor(a1, 2, 64);
        a0 += __shfl_xor(a0, 4, 64);
        a1 += __shfl_xor(a1, 4, 64);
        a0 += __shfl_xor(a0, 8, 64);
        a1 += __shfl_xor(a1, 8, 64);

        if (l == 0) {
            float2 r; r.x = a0 + bj0; r.y = a1 + bj1;
            *(float2*)op = r;
        }

        if (!more) break;
        va = ua; vb = ub; vc = uc; vd = ud;
        xp += xstep; op += ostep; t = tn;
    }
}

extern "C" void kernel_launch(void* const* d_in, const int* in_sizes, int n_in,
                              void* d_out, int out_size, void* d_ws, size_t ws_size,
                              hipStream_t stream) {
    const float* x    = (const float*)d_in[0];
    const float* W    = (const float*)d_in[1];
    const float* bias = (const float*)d_in[2];
    float* out        = (float*)d_out;

    const int B = in_sizes[0] / (13 * 256);   // 65536 (element count, as verified)

    // 3072 blocks x 4 waves = 12288 waves = 12 j-values x 1024 chunks.
    const int blocks = 3072;
    const int nwpj = (blocks * 4) / 12;       // 1024 waves per joint
    detok_kernel<<<blocks, 256, 0, stream>>>(x, W, bias, out, B, nwpj);
}